// Round 5
// baseline (120.589 us; speedup 1.0000x reference)
//
#include <hip/hip_runtime.h>
#include <math.h>

#define N 1024
#define C 81
#define F 1024
#define K 100
#define NC1 80              // C-1 foreground classes
#define MAXC (NC1 * N)
#define HBASE 0x3D00        // hist bucket base: float bits >>16 of 0.03125
#define HSIZE 1024          // covers score in (0.05, 1]
#define SELCAP 2048         // LDS select capacity

#define SCORE_THRESH 0.05f
#define NMS_THRESH   0.5f
#define BBOX_CLIP    4.135166556742356f   // log(1000/16)
#define IMG_W1       1215.0f
#define IMG_H1       799.0f

typedef unsigned long long u64;
typedef unsigned int u32;

// padded to separate cachelines
struct Sync {
    int flag_init; int p0[31];
    int done1;     int p1[31];
    int done2;     int p2[31];
    int flag3;     int p3[31];
    int counter;   int p4[31];
};

// One persistent kernel, 256 blocks x 256 threads. Phases linked by
// device-scope counters + agent fences (per-XCD L2 non-coherence).
// Co-residency safe: 34KB LDS -> >=4 blocks/CU, grid == 256 <= CU count.
__global__ __launch_bounds__(256) void k_fused(
    const float* __restrict__ logits, const float* __restrict__ boxreg,
    const float* __restrict__ pboxes, const float* __restrict__ feats,
    float* __restrict__ probsT, float4* __restrict__ decT,
    u64* __restrict__ ckey, int* __restrict__ hist, int* __restrict__ corder,
    float* __restrict__ sel_score, int* __restrict__ sel_flat,
    Sync* sync, float* __restrict__ out)
{
    const int b = blockIdx.x, tid = threadIdx.x;
    __shared__ __align__(16) char smem[33792];
    u64*    skey64 = (u64*)smem;               // 8 KB   [NMS]
    int*    scnt   = (int*)(smem + 8192);      // 1 KB   [NMS scan / select partial]
    float4* sbox   = (float4*)(smem + 9216);   // 16 KB  [NMS boxes / select keys]
    float*  sarea  = (float*)(smem + 25600);   // 4 KB
    int*    skeep  = (int*)(smem + 29696);     // 4 KB
    __shared__ int sb_bstar, scount;
    __shared__ u64 wk[4];
    __shared__ int wp[4];

    // ---- init (block 0; overlaps other blocks' phase A) ----
    if (b == 0) {
        for (int i = tid; i < HSIZE; i += 256) hist[i] = 0;
        if (tid == 0) { sync->done1 = 0; sync->done2 = 0; sync->flag3 = 0; sync->counter = 0; }
        __syncthreads();
        if (tid == 0) {
            __builtin_amdgcn_fence(__ATOMIC_RELEASE, "agent");
            __atomic_store_n(&sync->flag_init, 1, __ATOMIC_RELEASE);
        }
    }

    // ---- phase A: softmax + decode + clip (one wave per proposal) ----
    {
        int n = b * 4 + (tid >> 6);
        int t = tid & 63;

        float v1 = logits[n * C + t];
        float v2 = (t < C - 64) ? logits[n * C + 64 + t] : -INFINITY;
        float m = fmaxf(v1, v2);
        for (int off = 32; off; off >>= 1) m = fmaxf(m, __shfl_xor(m, off));
        float e1 = expf(v1 - m);
        float e2 = (t < C - 64) ? expf(v2 - m) : 0.0f;
        float s = e1 + e2;
        for (int off = 32; off; off >>= 1) s += __shfl_xor(s, off);

        probsT[t * N + n] = e1 / s;
        if (t < C - 64) probsT[(64 + t) * N + n] = e2 / s;

        float bx1 = pboxes[n * 4 + 0], by1 = pboxes[n * 4 + 1];
        float bx2 = pboxes[n * 4 + 2], by2 = pboxes[n * 4 + 3];
        float w  = bx2 - bx1 + 1.0f, h = by2 - by1 + 1.0f;
        float cx = bx1 + 0.5f * w,  cy = by1 + 0.5f * h;

        #pragma unroll
        for (int rep = 0; rep < 2; ++rep) {
            int cl = t + rep * 64;
            if (cl >= C) break;
            const float* r = boxreg + (size_t)n * (C * 4) + cl * 4;
            float dx = r[0] / 10.0f, dy = r[1] / 10.0f;
            float dw = fminf(r[2] / 5.0f, BBOX_CLIP);
            float dh = fminf(r[3] / 5.0f, BBOX_CLIP);

            float pcx = dx * w + cx, pcy = dy * h + cy;
            float pw = expf(dw) * w, ph = expf(dh) * h;

            float x1 = pcx - 0.5f * pw,        y1 = pcy - 0.5f * ph;
            float x2 = pcx + 0.5f * pw - 1.0f, y2 = pcy + 0.5f * ph - 1.0f;

            x1 = fminf(fmaxf(x1, 0.0f), IMG_W1);
            y1 = fminf(fmaxf(y1, 0.0f), IMG_H1);
            x2 = fminf(fmaxf(x2, 0.0f), IMG_W1);
            y2 = fminf(fmaxf(y2, 0.0f), IMG_H1);

            decT[(size_t)cl * N + n] = make_float4(x1, y1, x2, y2);
        }
    }
    __syncthreads();
    if (tid == 0) {
        while (__atomic_load_n(&sync->flag_init, __ATOMIC_RELAXED) != 1) ;
        __builtin_amdgcn_fence(__ATOMIC_RELEASE, "agent");
        atomicAdd(&sync->done1, 1);
    }

    if (b >= 100) return;          // blocks 100..255: phase A only

    // ---- phase B: per-class compact -> sort -> sequential NMS ----
    if (b < NC1) {
        if (tid == 0) { while (__atomic_load_n(&sync->done1, __ATOMIC_RELAXED) != 256) ; }
        __syncthreads();
        __builtin_amdgcn_fence(__ATOMIC_ACQUIRE, "agent");

        const int c = b, t = tid;
        const float4* prow = (const float4*)(probsT + (size_t)(c + 1) * N);
        float4 s4 = prow[t];
        int f0 = s4.x > SCORE_THRESH, f1 = s4.y > SCORE_THRESH;
        int f2 = s4.z > SCORE_THRESH, f3 = s4.w > SCORE_THRESH;
        int mycount = f0 + f1 + f2 + f3;
        scnt[t] = mycount;
        __syncthreads();
        for (int off = 1; off < 256; off <<= 1) {
            int v = scnt[t];
            int a = (t >= off) ? scnt[t - off] : 0;
            __syncthreads();
            scnt[t] = v + a;
            __syncthreads();
        }
        int base = scnt[t] - mycount;
        int V = scnt[255];
        {
            int p0 = t * 4, pos = base;
            if (f0) skey64[pos++] = ((u64)__float_as_uint(s4.x) << 32) | (u32)~(u32)(p0);
            if (f1) skey64[pos++] = ((u64)__float_as_uint(s4.y) << 32) | (u32)~(u32)(p0 + 1);
            if (f2) skey64[pos++] = ((u64)__float_as_uint(s4.z) << 32) | (u32)~(u32)(p0 + 2);
            if (f3) skey64[pos++] = ((u64)__float_as_uint(s4.w) << 32) | (u32)~(u32)(p0 + 3);
        }
        __syncthreads();

        if (V > 0 && V <= 64) {
            if (t < 64) {
                int lane = t;
                u64 key = (lane < V) ? skey64[lane] : 0ull;
                for (int k = 2; k <= 64; k <<= 1) {
                    for (int j = k >> 1; j > 0; j >>= 1) {
                        u64 other = __shfl_xor(key, j);
                        bool takeMax = (((lane & j) == 0) == ((lane & k) == 0));
                        bool gt = key > other;
                        key = (takeMax == gt) ? key : other;
                    }
                }
                bool act = key != 0ull;
                float4 bb = make_float4(0.f, 0.f, 0.f, 0.f);
                float area = 0.0f;
                if (act) {
                    int idx = (int)(~(u32)(key & 0xffffffffu));
                    corder[c * N + lane] = idx;
                    bb = decT[(size_t)(c + 1) * N + idx];
                    area = (bb.z - bb.x + 1.0f) * (bb.w - bb.y + 1.0f);
                }
                int kept = act ? 1 : 0;
                for (int i = 0; i + 1 < V; ++i) {
                    int   ki  = __shfl(kept, i);
                    float bix = __shfl(bb.x, i), biy = __shfl(bb.y, i);
                    float biz = __shfl(bb.z, i), biw = __shfl(bb.w, i);
                    float ai  = __shfl(area, i);
                    if (ki && lane > i && kept) {
                        float lx = fmaxf(bix, bb.x), ly = fmaxf(biy, bb.y);
                        float rx = fminf(biz, bb.z), ry = fminf(biw, bb.w);
                        float ww = fmaxf(rx - lx + 1.0f, 0.0f);
                        float hh = fmaxf(ry - ly + 1.0f, 0.0f);
                        float inter = ww * hh;
                        float iou = inter / (ai + area - inter);
                        if (iou > NMS_THRESH) kept = 0;
                    }
                }
                if (kept) {
                    int pos = atomicAdd(&sync->counter, 1);
                    u32 sb = (u32)(key >> 32);
                    ckey[pos] = ((u64)sb << 32) | (u64)(u32)~(u32)(c * N + lane);
                    atomicAdd(&hist[(int)(sb >> 16) - HBASE], 1);
                }
            }
        } else if (V > 64) {
            int P = 128;
            while (P < V) P <<= 1;
            for (int i = V + t; i < P; i += 256) skey64[i] = 0ull;
            __syncthreads();
            for (int k = 2; k <= P; k <<= 1) {
                for (int j = k >> 1; j > 0; j >>= 1) {
                    for (int i = t; i < P; i += 256) {
                        int ixj = i ^ j;
                        if (ixj > i) {
                            u64 a = skey64[i], bb2 = skey64[ixj];
                            bool desc = ((i & k) == 0);
                            if (desc ? (a < bb2) : (a > bb2)) { skey64[i] = bb2; skey64[ixj] = a; }
                        }
                    }
                    __syncthreads();
                }
            }
            for (int p = t; p < V; p += 256) {
                int idx = (int)(~(u32)(skey64[p] & 0xffffffffu));
                corder[c * N + p] = idx;
                float4 bb2 = decT[(size_t)(c + 1) * N + idx];
                sbox[p]  = bb2;
                sarea[p] = (bb2.z - bb2.x + 1.0f) * (bb2.w - bb2.y + 1.0f);
                skeep[p] = 1;
            }
            __syncthreads();
            for (int i = 0; i < V; ++i) {
                if (skeep[i]) {
                    float4 bi = sbox[i];
                    float  ai = sarea[i];
                    for (int j = i + 1 + t; j < V; j += 256) {
                        if (skeep[j]) {
                            float4 bj = sbox[j];
                            float lx = fmaxf(bi.x, bj.x), ly = fmaxf(bi.y, bj.y);
                            float rx = fminf(bi.z, bj.z), ry = fminf(bi.w, bj.w);
                            float ww = fmaxf(rx - lx + 1.0f, 0.0f);
                            float hh = fmaxf(ry - ly + 1.0f, 0.0f);
                            float inter = ww * hh;
                            float iou = inter / (ai + sarea[j] - inter);
                            if (iou > NMS_THRESH) skeep[j] = 0;
                        }
                    }
                }
                __syncthreads();
            }
            for (int p = t; p < V; p += 256) {
                if (skeep[p]) {
                    int pos = atomicAdd(&sync->counter, 1);
                    u32 sb = (u32)(skey64[p] >> 32);
                    ckey[pos] = ((u64)sb << 32) | (u64)(u32)~(u32)(c * N + p);
                    atomicAdd(&hist[(int)(sb >> 16) - HBASE], 1);
                }
            }
        }
        __syncthreads();
        if (tid == 0) {
            __builtin_amdgcn_fence(__ATOMIC_RELEASE, "agent");
            atomicAdd(&sync->done2, 1);
        }
    }

    // ---- phase C: radix-select + bitonic top-K (block 0, 256 threads) ----
    if (b == 0) {
        if (tid == 0) { while (__atomic_load_n(&sync->done2, __ATOMIC_RELAXED) != NC1) ; }
        __syncthreads();
        __builtin_amdgcn_fence(__ATOMIC_ACQUIRE, "agent");

        const int t = tid;
        int* partial = scnt;          // alias (1 KB)
        u64* keys = (u64*)sbox;       // alias (16 KB == SELCAP*8)
        int M = sync->counter;
        if (t == 0) { sb_bstar = 0; scount = 0; }

        int lo = t * 4;
        int h0 = hist[lo], h1 = hist[lo + 1], h2 = hist[lo + 2], h3 = hist[lo + 3];
        int lsum = h0 + h1 + h2 + h3;
        partial[t] = lsum;
        __syncthreads();
        for (int off = 1; off < 256; off <<= 1) {        // suffix scan
            int v = partial[t];
            int a = (t + off < 256) ? partial[t + off] : 0;
            __syncthreads();
            partial[t] = v + a;
            __syncthreads();
        }
        int basek = partial[t] - lsum;                   // keys above my 4 buckets
        if (basek < K && basek + lsum >= K) {
            int hh[4] = {h0, h1, h2, h3};
            int run = basek;
            for (int bb = 3; bb >= 0; --bb) {
                if (run < K && run + hh[bb] >= K) { sb_bstar = lo + bb; break; }
                run += hh[bb];
            }
        }
        __syncthreads();
        int bstar = sb_bstar;

        for (int p = t; p < M; p += 256) {
            u64 kk = ckey[p];
            int bb = (int)((kk >> 48) & 0xFFFF) - HBASE;
            if (bb >= bstar) {
                int pos = atomicAdd(&scount, 1);
                if (pos < SELCAP) keys[pos] = kk;
            }
        }
        __syncthreads();
        int cnt = scount;

        if (cnt <= SELCAP) {
            int P = 128;
            while (P < cnt) P <<= 1;
            for (int i = cnt + t; i < P; i += 256) keys[i] = 0ull;
            __syncthreads();
            for (int k = 2; k <= P; k <<= 1) {
                for (int j = k >> 1; j > 0; j >>= 1) {
                    for (int i = t; i < P; i += 256) {
                        int ixj = i ^ j;
                        if (ixj > i) {
                            u64 a = keys[i], bb2 = keys[ixj];
                            bool desc = ((i & k) == 0);
                            if (desc ? (a < bb2) : (a > bb2)) { keys[i] = bb2; keys[ixj] = a; }
                        }
                    }
                    __syncthreads();
                }
            }
            if (t < K) {
                u64 key = keys[t];
                sel_score[t] = __uint_as_float((u32)(key >> 32));
                sel_flat[t]  = (int)(~(u32)(key & 0xffffffffu));
            }
        } else {
            // exact fallback (tie flood): K rounds of argmax, 4 waves
            for (int k = 0; k < K; ++k) {
                u64 key = 0ull; int pos = -1;
                for (int p = t; p < M; p += 256) {
                    u64 kk = ckey[p];
                    if (kk > key) { key = kk; pos = p; }
                }
                for (int off = 32; off; off >>= 1) {
                    u64 ok2 = __shfl_down(key, off);
                    int op = __shfl_down(pos, off);
                    if (ok2 > key) { key = ok2; pos = op; }
                }
                if ((t & 63) == 0) { wk[t >> 6] = key; wp[t >> 6] = pos; }
                __syncthreads();
                if (t == 0) {
                    for (int w = 1; w < 4; ++w)
                        if (wk[w] > key) { key = wk[w]; pos = wp[w]; }
                    if (key != 0ull) {
                        sel_score[k] = __uint_as_float((u32)(key >> 32));
                        sel_flat[k]  = (int)(~(u32)(key & 0xffffffffu));
                        ckey[pos] = 0ull;
                    } else { sel_score[k] = 0.0f; sel_flat[k] = 0; }
                }
                __syncthreads();
            }
        }
        __syncthreads();
        if (tid == 0) {
            __builtin_amdgcn_fence(__ATOMIC_RELEASE, "agent");
            __atomic_store_n(&sync->flag3, 1, __ATOMIC_RELEASE);
        }
    }

    // ---- phase D: gather (blocks 0..99) ----
    if (tid == 0 && b != 0) {
        while (__atomic_load_n(&sync->flag3, __ATOMIC_RELAXED) != 1) ;
    }
    __syncthreads();
    __builtin_amdgcn_fence(__ATOMIC_ACQUIRE, "agent");
    {
        int k = b, t = tid;
        float s = sel_score[k];
        bool ok = s > 0.0f;
        float4 bb = make_float4(0.f, 0.f, 0.f, 0.f);
        int label = 0, orig = 0;
        if (ok) {
            int flat = sel_flat[k];
            int c = flat >> 10;              // N = 1024
            orig  = corder[flat];
            bb    = decT[(size_t)(c + 1) * N + orig];
            label = c + 1;
        }
        if (t == 0) {
            out[k * 4 + 0] = bb.x; out[k * 4 + 1] = bb.y;
            out[k * 4 + 2] = bb.z; out[k * 4 + 3] = bb.w;
            out[K * 4 + k] = ok ? s : 0.0f;
            out[K * 4 + K + K * F + k] = (float)label;
        }
        const float4* src = (const float4*)(feats + (size_t)orig * F);
        float4* dst = (float4*)(out + K * 4 + K + (size_t)k * F);
        float4 z = make_float4(0.f, 0.f, 0.f, 0.f);
        dst[t] = ok ? src[t] : z;            // 256 threads x float4 == F
    }
}

// ---------------------------------------------------------------------------
extern "C" void kernel_launch(void* const* d_in, const int* in_sizes, int n_in,
                              void* d_out, int out_size, void* d_ws, size_t ws_size,
                              hipStream_t stream)
{
    const float* logits = (const float*)d_in[0];   // [N,C]
    const float* boxreg = (const float*)d_in[1];   // [N,C*4]
    const float* pboxes = (const float*)d_in[2];   // [N,4]
    const float* feats  = (const float*)d_in[3];   // [N,F]
    float* out = (float*)d_out;

    char* ws = (char*)d_ws;
    size_t off = 0;
    auto alloc = [&](size_t bytes) {
        size_t cur = off;
        off = (off + bytes + 255) & ~(size_t)255;
        return cur;
    };
    float*  probsT    = (float*) (ws + alloc(sizeof(float)  * C * N));
    float4* decT      = (float4*)(ws + alloc(sizeof(float4) * C * N));
    u64*    ckey      = (u64*)   (ws + alloc(sizeof(u64)    * MAXC));
    int*    hist      = (int*)   (ws + alloc(sizeof(int)    * HSIZE));
    int*    corder    = (int*)   (ws + alloc(sizeof(int)    * NC1 * N));
    float*  sel_score = (float*) (ws + alloc(sizeof(float)  * K));
    int*    sel_flat  = (int*)   (ws + alloc(sizeof(int)    * K));
    Sync*   sync      = (Sync*)  (ws + alloc(sizeof(Sync)));

    hipLaunchKernelGGL(k_fused, dim3(256), dim3(256), 0, stream,
                       logits, boxreg, pboxes, feats, probsT, decT,
                       ckey, hist, corder, sel_score, sel_flat, sync, out);
}